// Round 9
// baseline (233.647 us; speedup 1.0000x reference)
//
#include <hip/hip_runtime.h>
#include <cstdint>
#include <cstddef>

#define DI __device__ __forceinline__

typedef __attribute__((ext_vector_type(8))) short short8;    // 8 x bf16
typedef __attribute__((ext_vector_type(4))) float f32x4;     // 16x16 C/D
typedef __attribute__((ext_vector_type(16))) float f32x16;   // 32x32 C/D
typedef unsigned int u32;
typedef unsigned short u16;

// ---------- bf16 helpers (RNE, matching jnp astype bfloat16) ----------
DI u16 rne_bf16(float f) {
  union { float f; u32 u; } v; v.f = f;
  u32 b = v.u;
  return (u16)((b + 0x7fffu + ((b >> 16) & 1u)) >> 16);
}
DI float bf2f(u16 h) {
  union { u32 u; float f; } v; v.u = ((u32)h) << 16;
  return v.f;
}
// packed RNE f32x2 -> bf16x2 (lo=a, hi=b)  [T12 primitive]
DI u32 cvtpk_bf16(float a, float b) {
  u32 r;
  asm("v_cvt_pk_bf16_f32 %0, %1, %2" : "=v"(r) : "v"(a), "v"(b));
  return r;
}

// ---------- async global->LDS, 16B per lane ----------
DI void gl2lds16(const void* g, void* l) {
  __builtin_amdgcn_global_load_lds(
      (const __attribute__((address_space(1))) u32*)g,
      (__attribute__((address_space(3))) u32*)l, 16, 0, 0);
}

// compiler-fence + raw barrier
DI void bar() {
  asm volatile("" ::: "memory");
  __builtin_amdgcn_s_barrier();
  asm volatile("" ::: "memory");
}

// Stage a ROWS x 64(bf16) tile into LDS, row stride 128B, granule-XOR swizzle
// (slot g holds source granule g^(row&7)); ds_read_b128 fragment reads are
// ~2-way (free). LDS dest linear (gl2lds16 requirement); swizzle applied on
// the *global source* address (m173 pattern).
template<int ROWS, int NT>
DI void stage_swz(const u16* src, int ld, char* ldsb, int tid) {
  int wbase = tid & ~63;  // wave-uniform LDS base: base + lane*16 implicit
  #pragma unroll
  for (int c = 0; c < (ROWS * 8) / NT; ++c) {
    int g = c * NT + tid;
    int row = g >> 3;
    int sgr = (g & 7) ^ (row & 7);
    gl2lds16(src + row * ld + sgr * 8, ldsb + (size_t)(c * NT + wbase) * 16);
  }
}

// Read one 8-bf16 fragment from a swizzled tile: logical (row, k0..k0+7)
DI short8 lds_frag(const char* base, int row, int k0) {
  return *(const short8*)(base + row * 128 + ((k0 * 2) ^ ((row & 7) << 4)));
}

DI f32x4 mfma16(short8 a, short8 b, f32x4 c) {
  return __builtin_amdgcn_mfma_f32_16x16x32_bf16(a, b, c, 0, 0, 0);
}
DI f32x16 mfma32(short8 a, short8 b, f32x16 c) {
  return __builtin_amdgcn_mfma_f32_32x32x16_bf16(a, b, c, 0, 0, 0);
}

// ---------------- weight fp32->bf16 conversion (one launch) ----------------
__global__ __launch_bounds__(256) void cvt_w(
    const float* __restrict__ a, const float* __restrict__ b,
    const float* __restrict__ c, const float* __restrict__ d,
    u16* __restrict__ oa, u16* __restrict__ ob, u16* __restrict__ oc,
    u16* __restrict__ od) {
  int i = blockIdx.x * 256 + threadIdx.x;
  if (i < 442368) oa[i] = rne_bf16(a[i]);
  else if (i < 589824) ob[i - 442368] = rne_bf16(b[i - 442368]);
  else if (i < 1179648) oc[i - 589824] = rne_bf16(c[i - 589824]);
  else if (i < 1769472) od[i - 1179648] = rne_bf16(d[i - 1179648]);
}

// ---------------- LayerNorm: one wave per row, COALESCED (c = j*64+lane) ---
template<int INBF>
__global__ __launch_bounds__(256) void ln_k(
    const void* __restrict__ xin, const float* __restrict__ gam,
    const float* __restrict__ bet, u16* __restrict__ out) {
  int row = blockIdx.x * 4 + (threadIdx.x >> 6);
  int lane = threadIdx.x & 63;
  float v[6];
  if (INBF) {
    const u16* x = (const u16*)xin + (size_t)row * 384 + lane;
    #pragma unroll
    for (int j = 0; j < 6; ++j) v[j] = bf2f(x[j * 64]);
  } else {
    const float* x = (const float*)xin + (size_t)row * 384 + lane;
    #pragma unroll
    for (int j = 0; j < 6; ++j) v[j] = x[j * 64];
  }
  float s = 0.f;
  #pragma unroll
  for (int j = 0; j < 6; ++j) s += v[j];
  #pragma unroll
  for (int d = 1; d < 64; d <<= 1) s += __shfl_xor(s, d);
  float mu = s * (1.f / 384.f);
  float q = 0.f;
  #pragma unroll
  for (int j = 0; j < 6; ++j) { float t = v[j] - mu; q += t * t; }
  #pragma unroll
  for (int d = 1; d < 64; d <<= 1) q += __shfl_xor(q, d);
  float rstd = rsqrtf(q * (1.f / 384.f) + 1e-5f);
  #pragma unroll
  for (int j = 0; j < 6; ++j) {
    int c = j * 64 + lane;
    out[(size_t)row * 384 + c] = rne_bf16((v[j] - mu) * rstd * gam[c] + bet[c]);
  }
}

// ---------------- GEMM: C[m,n] = sum_k A[m,k] * W[n,k], fused epilogues ----
struct EpiP {
  const float* bias;
  const float* residf;
  const u16* residb;
  u16* outb;
  float* outf;
  u16* q; u16* k; u16* v;  // QKV targets (natural [B,H,N,D])
};

// Q pre-scale: SCALE * log2(e) so attention uses exp2 directly.
#define QSCALE 0.18033688011112042f

template<int EPI, int MT>  // 0=QKV, 1=proj+resid, 2=fc1+gelu, 3=fc2+resid->f32
__global__ __launch_bounds__(256) void gemm_bt(
    const u16* __restrict__ A, const u16* __restrict__ W, int K, int bnN,
    EpiP p) {
  constexpr int ABUF = MT * 128;  // bytes per A-buffer (MT rows x 64 x bf16)
  constexpr int NC = (MT == 128) ? 4 : 2;
  __shared__ char lds[2 * (ABUF + 16384)];
  int tid = threadIdx.x, lane = tid & 63, wid = tid >> 6;
  int wr = (MT == 128) ? (wid >> 1) * 64 : 0;
  int wcb = (MT == 128) ? (wid & 1) * 64 : wid * 32;
  int fr = lane & 15, k8 = lane >> 4;
  // XCD swizzle: chunk of nwg/8 consecutive wg per XCD
  int orig = blockIdx.x;
  int cpx = (int)gridDim.x >> 3;
  int wg = (orig & 7) * cpx + (orig >> 3);
  int bm = wg / bnN, bn = wg - bm * bnN;
  const u16* Ab = A + (size_t)bm * MT * K;
  const u16* Wb = W + (size_t)bn * 128 * K;

  stage_swz<MT, 256>(Ab, K, lds, tid);
  stage_swz<128, 256>(Wb, K, lds + ABUF, tid);

  f32x4 zz = {0.f, 0.f, 0.f, 0.f};
  f32x4 acc[4][NC];
  #pragma unroll
  for (int mr = 0; mr < 4; ++mr)
    #pragma unroll
    for (int nc = 0; nc < NC; ++nc) acc[mr][nc] = zz;

  asm volatile("s_waitcnt vmcnt(0)" ::: "memory");
  __syncthreads();

  int KT = K >> 6;
  for (int t = 0; t < KT; ++t) {
    char* base = lds + (size_t)(t & 1) * (ABUF + 16384);
    if (t + 1 < KT) {
      char* nb = lds + (size_t)((t + 1) & 1) * (ABUF + 16384);
      stage_swz<MT, 256>(Ab + (t + 1) * 64, K, nb, tid);
      stage_swz<128, 256>(Wb + (t + 1) * 64, K, nb + ABUF, tid);
    }
    #pragma unroll
    for (int ks = 0; ks < 2; ++ks) {
      int k0 = ks * 32 + k8 * 8;
      short8 av[4], bv[NC];
      #pragma unroll
      for (int mr = 0; mr < 4; ++mr) av[mr] = lds_frag(base, wr + mr * 16 + fr, k0);
      #pragma unroll
      for (int nc = 0; nc < NC; ++nc) bv[nc] = lds_frag(base + ABUF, wcb + nc * 16 + fr, k0);
      __builtin_amdgcn_s_setprio(1);
      #pragma unroll
      for (int mr = 0; mr < 4; ++mr)
        #pragma unroll
        for (int nc = 0; nc < NC; ++nc)
          acc[mr][nc] = mfma16(av[mr], bv[nc], acc[mr][nc]);
      __builtin_amdgcn_s_setprio(0);
    }
    if (t + 1 < KT) {  // skip dead drain+barrier on the last iteration
      asm volatile("s_waitcnt vmcnt(0)" ::: "memory");
      __syncthreads();
    }
  }

  // epilogue: C/D layout col=lane&15, row=(lane>>4)*4+reg  [m89/m91]
  #pragma unroll
  for (int mr = 0; mr < 4; ++mr)
    #pragma unroll
    for (int nc = 0; nc < NC; ++nc)
      #pragma unroll
      for (int r = 0; r < 4; ++r) {
        int m = bm * MT + wr + mr * 16 + k8 * 4 + r;
        int o = bn * 128 + wcb + nc * 16 + fr;
        float val = acc[mr][nc][r];
        if constexpr (EPI == 0) {
          int tq = o / 384;
          int rem = o - tq * 384;
          int hh = rem >> 6, d = rem & 63;
          int b = m >> 11, n = m & 2047;
          float sv = (tq == 0) ? val * QSCALE : val;  // pre-scale Q
          u16 bvs = rne_bf16(sv);
          size_t qk = (((size_t)(b * 6 + hh)) * 2048 + n) * 64 + d;
          if (tq == 0) p.q[qk] = bvs;
          else if (tq == 1) p.k[qk] = bvs;
          else p.v[qk] = bvs;            // natural layout; transposed later
        } else if constexpr (EPI == 1) {
          size_t idx = (size_t)m * 384 + o;
          float r2 = p.residf[idx] + val + p.bias[o];
          p.outb[idx] = rne_bf16(r2);
        } else if constexpr (EPI == 2) {
          size_t idx = (size_t)m * 1536 + o;
          float z = val + p.bias[o];
          float gl = 0.5f * z * (1.f + erff(z * 0.70710678118654752f));
          p.outb[idx] = rne_bf16(gl);
        } else {
          size_t idx = (size_t)m * 384 + o;
          float r2 = bf2f(p.residb[idx]) + val + p.bias[o];
          p.outf[idx] = bf2f(rne_bf16(r2));
        }
      }
}

// ---------------- V transpose: v[bh][n][d] -> vt[bh][d][n] ------------------
__global__ __launch_bounds__(256) void vtr_k(
    const u16* __restrict__ v, u16* __restrict__ vt) {
  __shared__ u16 t[64 * 74];
  int tid = threadIdx.x;
  int n0 = blockIdx.x * 64, bh = blockIdx.y;
  const u16* src = v + ((size_t)bh * 2048 + n0) * 64;
  #pragma unroll
  for (int it = 0; it < 2; ++it) {
    int row = it * 32 + (tid >> 3), c8 = tid & 7;
    *(short8*)&t[row * 74 + c8 * 8] = *(const short8*)(src + row * 64 + c8 * 8);
  }
  __syncthreads();
  int dp = tid >> 3;   // 0..31: d-pair (2dp, 2dp+1)
  int ng = tid & 7;    // 0..7: n-group of 8
  u16 lo[8], hi[8];
  #pragma unroll
  for (int j = 0; j < 8; ++j) {
    u32 a = *(const u32*)&t[(ng * 8 + j) * 74 + dp * 2];
    lo[j] = (u16)a; hi[j] = (u16)(a >> 16);
  }
  u16* dst = vt + ((size_t)bh * 64 + 2 * dp) * 2048 + n0 + ng * 8;
  *(short8*)dst = *(short8*)&lo[0];
  *(short8*)(dst + 2048) = *(short8*)&hi[0];
}

// ---------------- Flash attention (KV-split=4, no-max softmax, T12) --------
// 4 waves x 32 q-rows; KV window 512 = 8 tiles of 64; 2-deep LDS dbuf
// (K,V only — no P buffer; LDS 32KB -> 5 blocks/CU, grid 1536 -> ~5/CU).
// Swapped QK^T on 32x32x16: lane owns q=lane&31, P-row in regs; pack via
// v_cvt_pk_bf16_f32; cross-half k exchange via __shfl_xor(.,32).
// Partials written as bf16 (exact-fit in act region; error << 1 ulp of ao).
__global__ __launch_bounds__(256) void attn_k(
    const u16* __restrict__ Qg, const u16* __restrict__ Kg,
    const u16* __restrict__ Vg, u16* __restrict__ Op, float* __restrict__ lp) {
  __shared__ char lds[32768];  // K:2x8192 | V:2x8192 @16384
  int tid = threadIdx.x, lane = tid & 63, wid = tid >> 6;
  int l31 = lane & 31, h = lane >> 5;
  int qt = blockIdx.x, bh = blockIdx.y, z = blockIdx.z;
  const u16* Qb = Qg + (size_t)bh * 2048 * 64;
  const u16* Kb = Kg + ((size_t)bh * 2048 + z * 512) * 64;
  const u16* Vb = Vg + (size_t)bh * 64 * 2048 + z * 512;
  int qr0 = qt * 128 + wid * 32;

  // Q as B-operand frags: col=q=lane&31, k-dim d=(lane>>5)*8+j (+16m)
  short8 qf[4];
  #pragma unroll
  for (int m = 0; m < 4; ++m)
    qf[m] = *(const short8*)(Qb + (size_t)(qr0 + l31) * 64 + m * 16 + h * 8);

  f32x16 oacc[2];
  #pragma unroll
  for (int dt = 0; dt < 2; ++dt)
    #pragma unroll
    for (int r = 0; r < 16; ++r) oacc[dt][r] = 0.f;
  float lrun = 0.f;

  #define STAGE(t)                                                              \
    stage_swz<64, 256>(Kb + (size_t)(t) * 4096, 64, lds + ((t) & 1) * 8192, tid); \
    stage_swz<64, 256>(Vb + (t) * 64, 2048, lds + 16384 + ((t) & 1) * 8192, tid);

  STAGE(0);
  asm volatile("s_waitcnt vmcnt(0)" ::: "memory");
  bar();

  for (int t = 0; t < 8; ++t) {
    if (t + 1 < 8) { STAGE(t + 1); }
    char* kbase = lds + (t & 1) * 8192;
    char* vbase = lds + 16384 + (t & 1) * 8192;

    // S^T = K Q^T (pre-scaled): s[kt] rows k=(r&3)+8*(r>>2)+4h, col q=l31
    f32x16 s[2];
    #pragma unroll
    for (int kt = 0; kt < 2; ++kt) {
      #pragma unroll
      for (int r = 0; r < 16; ++r) s[kt][r] = 0.f;
      short8 kf[4];
      #pragma unroll
      for (int m = 0; m < 4; ++m)
        kf[m] = lds_frag(kbase, kt * 32 + l31, m * 16 + h * 8);
      __builtin_amdgcn_s_setprio(1);
      #pragma unroll
      for (int m = 0; m < 4; ++m) s[kt] = mfma32(kf[m], qf[m], s[kt]);
      __builtin_amdgcn_s_setprio(0);
    }
    // P = exp2(S); per-lane scalar row-sum
    #pragma unroll
    for (int kt = 0; kt < 2; ++kt)
      #pragma unroll
      for (int r = 0; r < 16; ++r) {
        float pv = exp2f(s[kt][r]);
        s[kt][r] = pv;
        lrun += pv;
      }
    // pack + cross-half exchange + PV (all in-register, no P LDS)
    #pragma unroll
    for (int kt = 0; kt < 2; ++kt) {
      u32 ow[4][2], pw[4][2];
      #pragma unroll
      for (int B = 0; B < 4; ++B) {
        ow[B][0] = cvtpk_bf16(s[kt][4 * B + 0], s[kt][4 * B + 1]);
        ow[B][1] = cvtpk_bf16(s[kt][4 * B + 2], s[kt][4 * B + 3]);
      }
      #pragma unroll
      for (int B = 0; B < 4; ++B) {
        pw[B][0] = __shfl_xor(ow[B][0], 32);
        pw[B][1] = __shfl_xor(ow[B][1], 32);
      }
      #pragma unroll
      for (int m = 0; m < 2; ++m) {
        union { u32 w[4]; short8 v; } af;
        af.w[0] = h ? pw[2 * m + 1][0] : ow[2 * m][0];
        af.w[1] = h ? pw[2 * m + 1][1] : ow[2 * m][1];
        af.w[2] = h ? ow[2 * m + 1][0] : pw[2 * m][0];
        af.w[3] = h ? ow[2 * m + 1][1] : pw[2 * m][1];
        int K0 = kt * 32 + m * 16;
        short8 vf0 = lds_frag(vbase, l31, K0 + h * 8);
        short8 vf1 = lds_frag(vbase, 32 + l31, K0 + h * 8);
        __builtin_amdgcn_s_setprio(1);
        oacc[0] = mfma32(af.v, vf0, oacc[0]);
        oacc[1] = mfma32(af.v, vf1, oacc[1]);
        __builtin_amdgcn_s_setprio(0);
      }
    }
    asm volatile("s_waitcnt vmcnt(0)" ::: "memory");
    if (t < 7) bar();
  }
  #undef STAGE

  float ltot = lrun + __shfl_xor(lrun, 32);
  size_t rowb = (size_t)z * 49152 + (size_t)bh * 2048;
  // O: row q=(r&3)+8*(r>>2)+4h, col d=dt*32+l31; bf16 partials
  #pragma unroll
  for (int dt = 0; dt < 2; ++dt)
    #pragma unroll
    for (int r = 0; r < 16; ++r) {
      int qrow = qr0 + (r & 3) + 8 * (r >> 2) + 4 * h;
      Op[(rowb + qrow) * 64 + dt * 32 + l31] = rne_bf16(oacc[dt][r]);
    }
  if (lane < 32) lp[rowb + qr0 + l31] = ltot;
}

// ---------------- merge the four KV-split partials -> ao bf16 ---------------
__global__ __launch_bounds__(256) void attn_merge(
    const u16* __restrict__ Op, const float* __restrict__ lp,
    u16* __restrict__ ao) {
  int row = blockIdx.x * 4 + (threadIdx.x >> 6);  // bh*2048+n, 49152 rows
  int d = threadIdx.x & 63;
  float l = 0.f, v = 0.f;
  #pragma unroll
  for (int zz = 0; zz < 4; ++zz) {
    l += lp[zz * 49152 + row];
    v += bf2f(Op[((size_t)(zz * 49152 + row)) * 64 + d]);
  }
  v /= l;
  int bh = row >> 11, n = row & 2047;
  int b = bh / 6, hh = bh - b * 6;
  ao[((size_t)(b * 2048 + n)) * 384 + hh * 64 + d] = rne_bf16(v);
}

// ---------------- launch ----------------------------------------------------
extern "C" void kernel_launch(void* const* d_in, const int* in_sizes, int n_in,
                              void* d_out, int out_size, void* d_ws, size_t ws_size,
                              hipStream_t stream) {
  const float* x     = (const float*)d_in[0];
  const float* ln1g  = (const float*)d_in[1];
  const float* ln1b  = (const float*)d_in[2];
  const float* wqkv  = (const float*)d_in[3];
  const float* wproj = (const float*)d_in[4];
  const float* bproj = (const float*)d_in[5];
  const float* ln2g  = (const float*)d_in[6];
  const float* ln2b  = (const float*)d_in[7];
  const float* wfc1  = (const float*)d_in[8];
  const float* bfc1  = (const float*)d_in[9];
  const float* wfc2  = (const float*)d_in[10];
  const float* bfc2  = (const float*)d_in[11];
  float* out = (float*)d_out;

  char* w = (char*)d_ws;
  u16* h1     = (u16*)w; w += 6291456;   // LN1 out bf16 [8192][384]
  u16* x2     = (u16*)w; w += 6291456;   // post-attn residual bf16
  u16* h2     = (u16*)w; w += 6291456;   // v_nat (pre-attn) / lpart (attn) / LN2 out
  u16* qb     = (u16*)w; w += 6291456;   // Q (pre-scaled) [B,H,N,D]
  u16* kb     = (u16*)w; w += 6291456;   // K [B,H,N,D]
  u16* vtb    = (u16*)w; w += 6291456;   // V^T [B,H,D,N]
  u16* ao     = (u16*)w; w += 6291456;   // attn out bf16 [8192][384]
  u16* act    = (u16*)w; w += 25165824;  // Opart bf16 (attn) / gelu out
  u16* wqkvb  = (u16*)w; w += 884736;
  u16* wprojb = (u16*)w; w += 294912;
  u16* wfc1b  = (u16*)w; w += 1179648;
  u16* wfc2b  = (u16*)w; w += 1179648;

  u16* v_nat   = h2;           // dead before ln2 writes h2
  u16* Opart   = act;          // 4*49152*64*2B = 25165824 B exactly
  float* lpart = (float*)h2;   // 4*49152*4B = 786KB; after vtr consumed v_nat

  cvt_w<<<6912, 256, 0, stream>>>(wqkv, wproj, wfc1, wfc2, wqkvb, wprojb, wfc1b, wfc2b);
  ln_k<0><<<2048, 256, 0, stream>>>(x, ln1g, ln1b, h1);
  {
    EpiP p{}; p.q = qb; p.k = kb; p.v = v_nat;
    gemm_bt<0, 64><<<1152, 256, 0, stream>>>(h1, wqkvb, 384, 9, p);
  }
  vtr_k<<<dim3(32, 24), 256, 0, stream>>>(v_nat, vtb);
  attn_k<<<dim3(16, 24, 4), 256, 0, stream>>>(qb, kb, vtb, Opart, lpart);
  attn_merge<<<12288, 256, 0, stream>>>(Opart, lpart, ao);
  {
    EpiP p{}; p.bias = bproj; p.residf = x; p.outb = x2;
    gemm_bt<1, 64><<<384, 256, 0, stream>>>(ao, wprojb, 384, 3, p);
  }
  ln_k<1><<<2048, 256, 0, stream>>>(x2, ln2g, ln2b, h2);
  {
    EpiP p{}; p.bias = bfc1; p.outb = act;
    gemm_bt<2, 128><<<768, 256, 0, stream>>>(h2, wfc1b, 384, 12, p);
  }
  {
    EpiP p{}; p.bias = bfc2; p.residb = x2; p.outf = out;
    gemm_bt<3, 64><<<384, 256, 0, stream>>>(act, wfc2b, 1536, 3, p);
  }
}

// Round 10
// 228.260 us; speedup vs baseline: 1.0236x; 1.0236x over previous
//
#include <hip/hip_runtime.h>
#include <cstdint>
#include <cstddef>

#define DI __device__ __forceinline__

typedef __attribute__((ext_vector_type(8))) short short8;    // 8 x bf16
typedef __attribute__((ext_vector_type(4))) float f32x4;     // 16x16 C/D
typedef __attribute__((ext_vector_type(16))) float f32x16;   // 32x32 C/D
typedef unsigned int u32;
typedef unsigned short u16;

// ---------- bf16 helpers (RNE, matching jnp astype bfloat16) ----------
DI u16 rne_bf16(float f) {
  union { float f; u32 u; } v; v.f = f;
  u32 b = v.u;
  return (u16)((b + 0x7fffu + ((b >> 16) & 1u)) >> 16);
}
DI float bf2f(u16 h) {
  union { u32 u; float f; } v; v.u = ((u32)h) << 16;
  return v.f;
}
// packed RNE f32x2 -> bf16x2 (lo=a, hi=b)  [T12 primitive]
DI u32 cvtpk_bf16(float a, float b) {
  u32 r;
  asm("v_cvt_pk_bf16_f32 %0, %1, %2" : "=v"(r) : "v"(a), "v"(b));
  return r;
}

// ---------- async global->LDS, 16B per lane ----------
DI void gl2lds16(const void* g, void* l) {
  __builtin_amdgcn_global_load_lds(
      (const __attribute__((address_space(1))) u32*)g,
      (__attribute__((address_space(3))) u32*)l, 16, 0, 0);
}

// compiler-fence + raw barrier (no vmcnt drain — unlike __syncthreads)
DI void bar() {
  asm volatile("" ::: "memory");
  __builtin_amdgcn_s_barrier();
  asm volatile("" ::: "memory");
}

// Stage a ROWS x 64(bf16) tile into LDS, row stride 128B, granule-XOR swizzle
// (slot g holds source granule g^(row&7)); ds_read_b128 fragment reads are
// ~2-way (free). LDS dest linear (gl2lds16 requirement); swizzle applied on
// the *global source* address (m173 pattern).
template<int ROWS, int NT>
DI void stage_swz(const u16* src, int ld, char* ldsb, int tid) {
  int wbase = tid & ~63;  // wave-uniform LDS base: base + lane*16 implicit
  #pragma unroll
  for (int c = 0; c < (ROWS * 8) / NT; ++c) {
    int g = c * NT + tid;
    int row = g >> 3;
    int sgr = (g & 7) ^ (row & 7);
    gl2lds16(src + row * ld + sgr * 8, ldsb + (size_t)(c * NT + wbase) * 16);
  }
}

// Read one 8-bf16 fragment from a swizzled tile: logical (row, k0..k0+7)
DI short8 lds_frag(const char* base, int row, int k0) {
  return *(const short8*)(base + row * 128 + ((k0 * 2) ^ ((row & 7) << 4)));
}

DI f32x4 mfma16(short8 a, short8 b, f32x4 c) {
  return __builtin_amdgcn_mfma_f32_16x16x32_bf16(a, b, c, 0, 0, 0);
}
DI f32x16 mfma32(short8 a, short8 b, f32x16 c) {
  return __builtin_amdgcn_mfma_f32_32x32x16_bf16(a, b, c, 0, 0, 0);
}

// ---------------- weight fp32->bf16 conversion (one launch) ----------------
__global__ __launch_bounds__(256) void cvt_w(
    const float* __restrict__ a, const float* __restrict__ b,
    const float* __restrict__ c, const float* __restrict__ d,
    u16* __restrict__ oa, u16* __restrict__ ob, u16* __restrict__ oc,
    u16* __restrict__ od) {
  int i = blockIdx.x * 256 + threadIdx.x;
  if (i < 442368) oa[i] = rne_bf16(a[i]);
  else if (i < 589824) ob[i - 442368] = rne_bf16(b[i - 442368]);
  else if (i < 1179648) oc[i - 589824] = rne_bf16(c[i - 589824]);
  else if (i < 1769472) od[i - 1179648] = rne_bf16(d[i - 1179648]);
}

// ---------------- LayerNorm: one wave per row, COALESCED (c = j*64+lane) ---
template<int INBF>
__global__ __launch_bounds__(256) void ln_k(
    const void* __restrict__ xin, const float* __restrict__ gam,
    const float* __restrict__ bet, u16* __restrict__ out) {
  int row = blockIdx.x * 4 + (threadIdx.x >> 6);
  int lane = threadIdx.x & 63;
  float v[6];
  if (INBF) {
    const u16* x = (const u16*)xin + (size_t)row * 384 + lane;
    #pragma unroll
    for (int j = 0; j < 6; ++j) v[j] = bf2f(x[j * 64]);
  } else {
    const float* x = (const float*)xin + (size_t)row * 384 + lane;
    #pragma unroll
    for (int j = 0; j < 6; ++j) v[j] = x[j * 64];
  }
  float s = 0.f;
  #pragma unroll
  for (int j = 0; j < 6; ++j) s += v[j];
  #pragma unroll
  for (int d = 1; d < 64; d <<= 1) s += __shfl_xor(s, d);
  float mu = s * (1.f / 384.f);
  float q = 0.f;
  #pragma unroll
  for (int j = 0; j < 6; ++j) { float t = v[j] - mu; q += t * t; }
  #pragma unroll
  for (int d = 1; d < 64; d <<= 1) q += __shfl_xor(q, d);
  float rstd = rsqrtf(q * (1.f / 384.f) + 1e-5f);
  #pragma unroll
  for (int j = 0; j < 6; ++j) {
    int c = j * 64 + lane;
    out[(size_t)row * 384 + c] = rne_bf16((v[j] - mu) * rstd * gam[c] + bet[c]);
  }
}

// ---------------- GEMM: C[m,n] = sum_k A[m,k] * W[n,k], fused epilogues ----
// Counted-vmcnt 2-barrier pipeline (T3/T4-lite): stage(t+2) issued after the
// post-compute barrier; per-iter wait is vmcnt(SI) (next tile stays in
// flight) — never a full drain until the last iteration.
struct EpiP {
  const float* bias;
  const float* residf;
  const u16* residb;
  u16* outb;
  float* outf;
  u16* q; u16* k; u16* v;  // QKV targets (natural [B,H,N,D])
};

// Q pre-scale: SCALE * log2(e) so attention uses exp2 directly.
#define QSCALE 0.18033688011112042f

template<int EPI, int MT>  // 0=QKV, 1=proj+resid, 2=fc1+gelu, 3=fc2+resid->f32
__global__ __launch_bounds__(256) void gemm_bt(
    const u16* __restrict__ A, const u16* __restrict__ W, int K, int bnN,
    EpiP p) {
  constexpr int ABUF = MT * 128;  // bytes per A-buffer (MT rows x 64 x bf16)
  constexpr int NC = (MT == 128) ? 4 : 2;
  __shared__ char lds[2 * (ABUF + 16384)];
  int tid = threadIdx.x, lane = tid & 63, wid = tid >> 6;
  int wr = (MT == 128) ? (wid >> 1) * 64 : 0;
  int wcb = (MT == 128) ? (wid & 1) * 64 : wid * 32;
  int fr = lane & 15, k8 = lane >> 4;
  // XCD swizzle: chunk of nwg/8 consecutive wg per XCD
  int orig = blockIdx.x;
  int cpx = (int)gridDim.x >> 3;
  int wg = (orig & 7) * cpx + (orig >> 3);
  int bm = wg / bnN, bn = wg - bm * bnN;
  const u16* Ab = A + (size_t)bm * MT * K;
  const u16* Wb = W + (size_t)bn * 128 * K;

  #define GSTAGE(t)                                                            \
    stage_swz<MT, 256>(Ab + (t) * 64, K,                                       \
                       lds + (size_t)((t) & 1) * (ABUF + 16384), tid);         \
    stage_swz<128, 256>(Wb + (t) * 64, K,                                      \
                        lds + (size_t)((t) & 1) * (ABUF + 16384) + ABUF, tid);

  GSTAGE(0);
  GSTAGE(1);  // KT >= 6 always here

  f32x4 zz = {0.f, 0.f, 0.f, 0.f};
  f32x4 acc[4][NC];
  #pragma unroll
  for (int mr = 0; mr < 4; ++mr)
    #pragma unroll
    for (int nc = 0; nc < NC; ++nc) acc[mr][nc] = zz;

  int KT = K >> 6;
  for (int t = 0; t < KT; ++t) {
    if (t + 1 < KT) {  // wait only for tile t; tile t+1 stays in flight
      if constexpr (MT == 128) asm volatile("s_waitcnt vmcnt(8)" ::: "memory");
      else                     asm volatile("s_waitcnt vmcnt(6)" ::: "memory");
    } else {
      asm volatile("s_waitcnt vmcnt(0)" ::: "memory");
    }
    bar();
    char* base = lds + (size_t)(t & 1) * (ABUF + 16384);
    #pragma unroll
    for (int ks = 0; ks < 2; ++ks) {
      int k0 = ks * 32 + k8 * 8;
      short8 av[4], bv[NC];
      #pragma unroll
      for (int mr = 0; mr < 4; ++mr) av[mr] = lds_frag(base, wr + mr * 16 + fr, k0);
      #pragma unroll
      for (int nc = 0; nc < NC; ++nc) bv[nc] = lds_frag(base + ABUF, wcb + nc * 16 + fr, k0);
      __builtin_amdgcn_s_setprio(1);
      #pragma unroll
      for (int mr = 0; mr < 4; ++mr)
        #pragma unroll
        for (int nc = 0; nc < NC; ++nc)
          acc[mr][nc] = mfma16(av[mr], bv[nc], acc[mr][nc]);
      __builtin_amdgcn_s_setprio(0);
    }
    if (t + 2 < KT) {
      bar();          // all waves done reading buf (t&1)
      GSTAGE(t + 2);  // refill it
    }
  }
  #undef GSTAGE

  // epilogue: C/D layout col=lane&15, row=(lane>>4)*4+reg  [m89/m91]
  #pragma unroll
  for (int mr = 0; mr < 4; ++mr)
    #pragma unroll
    for (int nc = 0; nc < NC; ++nc)
      #pragma unroll
      for (int r = 0; r < 4; ++r) {
        int m = bm * MT + wr + mr * 16 + k8 * 4 + r;
        int o = bn * 128 + wcb + nc * 16 + fr;
        float val = acc[mr][nc][r];
        if constexpr (EPI == 0) {
          int tq = o / 384;
          int rem = o - tq * 384;
          int hh = rem >> 6, d = rem & 63;
          int b = m >> 11, n = m & 2047;
          float sv = (tq == 0) ? val * QSCALE : val;  // pre-scale Q
          u16 bvs = rne_bf16(sv);
          size_t qk = (((size_t)(b * 6 + hh)) * 2048 + n) * 64 + d;
          if (tq == 0) p.q[qk] = bvs;
          else if (tq == 1) p.k[qk] = bvs;
          else p.v[qk] = bvs;            // natural layout; transposed later
        } else if constexpr (EPI == 1) {
          size_t idx = (size_t)m * 384 + o;
          float r2 = p.residf[idx] + val + p.bias[o];
          p.outb[idx] = rne_bf16(r2);
        } else if constexpr (EPI == 2) {
          size_t idx = (size_t)m * 1536 + o;
          float z = val + p.bias[o];
          float gl = 0.5f * z * (1.f + erff(z * 0.70710678118654752f));
          p.outb[idx] = rne_bf16(gl);
        } else {
          size_t idx = (size_t)m * 384 + o;
          float r2 = bf2f(p.residb[idx]) + val + p.bias[o];
          p.outf[idx] = bf2f(rne_bf16(r2));
        }
      }
}

// ---------------- V transpose: v[bh][n][d] -> vt[bh][d][n] ------------------
__global__ __launch_bounds__(256) void vtr_k(
    const u16* __restrict__ v, u16* __restrict__ vt) {
  __shared__ u16 t[64 * 74];
  int tid = threadIdx.x;
  int n0 = blockIdx.x * 64, bh = blockIdx.y;
  const u16* src = v + ((size_t)bh * 2048 + n0) * 64;
  #pragma unroll
  for (int it = 0; it < 2; ++it) {
    int row = it * 32 + (tid >> 3), c8 = tid & 7;
    *(short8*)&t[row * 74 + c8 * 8] = *(const short8*)(src + row * 64 + c8 * 8);
  }
  __syncthreads();
  int dp = tid >> 3;   // 0..31: d-pair (2dp, 2dp+1)
  int ng = tid & 7;    // 0..7: n-group of 8
  u16 lo[8], hi[8];
  #pragma unroll
  for (int j = 0; j < 8; ++j) {
    u32 a = *(const u32*)&t[(ng * 8 + j) * 74 + dp * 2];
    lo[j] = (u16)a; hi[j] = (u16)(a >> 16);
  }
  u16* dst = vt + ((size_t)bh * 64 + 2 * dp) * 2048 + n0 + ng * 8;
  *(short8*)dst = *(short8*)&lo[0];
  *(short8*)(dst + 2048) = *(short8*)&hi[0];
}

// ---------------- Flash attention (KV-split=2, no-max softmax, T12) --------
// 4 waves x 32 q-rows; KV tile 64; 2-deep circular LDS with counted vmcnt
// (stage t+2 issued after post-compute barrier; wait vmcnt(4) only).
// Swapped QK^T on 32x32x16: lane owns q=lane&31, P-row in regs; pack via
// v_cvt_pk_bf16_f32; cross-half k exchange via __shfl_xor(.,32).
__global__ __launch_bounds__(256) void attn_k(
    const u16* __restrict__ Qg, const u16* __restrict__ Kg,
    const u16* __restrict__ Vg, float* __restrict__ Op, float* __restrict__ lp) {
  __shared__ char lds[32768];  // K:2x8192 | V:2x8192 @16384
  int tid = threadIdx.x, lane = tid & 63, wid = tid >> 6;
  int l31 = lane & 31, h = lane >> 5;
  int qt = blockIdx.x, bh = blockIdx.y, z = blockIdx.z;
  const u16* Qb = Qg + (size_t)bh * 2048 * 64;
  const u16* Kb = Kg + ((size_t)bh * 2048 + z * 1024) * 64;
  const u16* Vb = Vg + (size_t)bh * 64 * 2048 + z * 1024;
  int qr0 = qt * 128 + wid * 32;

  // Q as B-operand frags: col=q=lane&31, k-dim d=(lane>>5)*8+j (+16m)
  short8 qf[4];
  #pragma unroll
  for (int m = 0; m < 4; ++m)
    qf[m] = *(const short8*)(Qb + (size_t)(qr0 + l31) * 64 + m * 16 + h * 8);

  f32x16 oacc[2];
  #pragma unroll
  for (int dt = 0; dt < 2; ++dt)
    #pragma unroll
    for (int r = 0; r < 16; ++r) oacc[dt][r] = 0.f;
  float lrun = 0.f;

  #define STAGE(t)                                                              \
    stage_swz<64, 256>(Kb + (size_t)(t) * 4096, 64, lds + ((t) & 1) * 8192, tid); \
    stage_swz<64, 256>(Vb + (t) * 64, 2048, lds + 16384 + ((t) & 1) * 8192, tid);

  STAGE(0);
  STAGE(1);

  for (int t = 0; t < 16; ++t) {
    if (t + 1 < 16) { asm volatile("s_waitcnt vmcnt(4)" ::: "memory"); }
    else            { asm volatile("s_waitcnt vmcnt(0)" ::: "memory"); }
    bar();
    char* kbase = lds + (t & 1) * 8192;
    char* vbase = lds + 16384 + (t & 1) * 8192;

    // S^T = K Q^T (pre-scaled): s[kt] rows k=(r&3)+8*(r>>2)+4h, col q=l31
    f32x16 s[2];
    #pragma unroll
    for (int kt = 0; kt < 2; ++kt) {
      #pragma unroll
      for (int r = 0; r < 16; ++r) s[kt][r] = 0.f;
      short8 kf[4];
      #pragma unroll
      for (int m = 0; m < 4; ++m)
        kf[m] = lds_frag(kbase, kt * 32 + l31, m * 16 + h * 8);
      __builtin_amdgcn_s_setprio(1);
      #pragma unroll
      for (int m = 0; m < 4; ++m) s[kt] = mfma32(kf[m], qf[m], s[kt]);
      __builtin_amdgcn_s_setprio(0);
    }
    // P = exp2(S); per-lane scalar row-sum
    #pragma unroll
    for (int kt = 0; kt < 2; ++kt)
      #pragma unroll
      for (int r = 0; r < 16; ++r) {
        float pv = exp2f(s[kt][r]);
        s[kt][r] = pv;
        lrun += pv;
      }
    // pack + cross-half exchange + PV (all in-register, no P LDS)
    #pragma unroll
    for (int kt = 0; kt < 2; ++kt) {
      u32 ow[4][2], pw[4][2];
      #pragma unroll
      for (int B = 0; B < 4; ++B) {
        ow[B][0] = cvtpk_bf16(s[kt][4 * B + 0], s[kt][4 * B + 1]);
        ow[B][1] = cvtpk_bf16(s[kt][4 * B + 2], s[kt][4 * B + 3]);
      }
      #pragma unroll
      for (int B = 0; B < 4; ++B) {
        pw[B][0] = __shfl_xor(ow[B][0], 32);
        pw[B][1] = __shfl_xor(ow[B][1], 32);
      }
      #pragma unroll
      for (int m = 0; m < 2; ++m) {
        union { u32 w[4]; short8 v; } af;
        af.w[0] = h ? pw[2 * m + 1][0] : ow[2 * m][0];
        af.w[1] = h ? pw[2 * m + 1][1] : ow[2 * m][1];
        af.w[2] = h ? ow[2 * m + 1][0] : pw[2 * m][0];
        af.w[3] = h ? ow[2 * m + 1][1] : pw[2 * m][1];
        int K0 = kt * 32 + m * 16;
        short8 vf0 = lds_frag(vbase, l31, K0 + h * 8);
        short8 vf1 = lds_frag(vbase, 32 + l31, K0 + h * 8);
        __builtin_amdgcn_s_setprio(1);
        oacc[0] = mfma32(af.v, vf0, oacc[0]);
        oacc[1] = mfma32(af.v, vf1, oacc[1]);
        __builtin_amdgcn_s_setprio(0);
      }
    }
    if (t + 2 < 16) {
      bar();          // all waves done reading buf (t&1)
      STAGE(t + 2);   // refill it
    }
  }
  #undef STAGE

  float ltot = lrun + __shfl_xor(lrun, 32);
  size_t rowb = (size_t)z * 49152 + (size_t)bh * 2048;
  // O: row q=(r&3)+8*(r>>2)+4h, col d=dt*32+l31
  #pragma unroll
  for (int dt = 0; dt < 2; ++dt)
    #pragma unroll
    for (int r = 0; r < 16; ++r) {
      int qrow = qr0 + (r & 3) + 8 * (r >> 2) + 4 * h;
      Op[(rowb + qrow) * 64 + dt * 32 + l31] = oacc[dt][r];
    }
  if (lane < 32) lp[rowb + qr0 + l31] = ltot;
}

// ---------------- merge the two KV-split partials -> ao bf16 ---------------
__global__ __launch_bounds__(256) void attn_merge(
    const float* __restrict__ Op, const float* __restrict__ lp,
    u16* __restrict__ ao) {
  int row = blockIdx.x * 4 + (threadIdx.x >> 6);  // bh*2048+n, 49152 rows
  int d = threadIdx.x & 63;
  float l = lp[row] + lp[49152 + row];
  float v = (Op[(size_t)row * 64 + d] + Op[(size_t)(49152 + row) * 64 + d]) / l;
  int bh = row >> 11, n = row & 2047;
  int b = bh / 6, hh = bh - b * 6;
  ao[((size_t)(b * 2048 + n)) * 384 + hh * 64 + d] = rne_bf16(v);
}

// ---------------- launch ----------------------------------------------------
extern "C" void kernel_launch(void* const* d_in, const int* in_sizes, int n_in,
                              void* d_out, int out_size, void* d_ws, size_t ws_size,
                              hipStream_t stream) {
  const float* x     = (const float*)d_in[0];
  const float* ln1g  = (const float*)d_in[1];
  const float* ln1b  = (const float*)d_in[2];
  const float* wqkv  = (const float*)d_in[3];
  const float* wproj = (const float*)d_in[4];
  const float* bproj = (const float*)d_in[5];
  const float* ln2g  = (const float*)d_in[6];
  const float* ln2b  = (const float*)d_in[7];
  const float* wfc1  = (const float*)d_in[8];
  const float* bfc1  = (const float*)d_in[9];
  const float* wfc2  = (const float*)d_in[10];
  const float* bfc2  = (const float*)d_in[11];
  float* out = (float*)d_out;

  char* w = (char*)d_ws;
  u16* h1     = (u16*)w; w += 6291456;   // LN1 out bf16 [8192][384]
  u16* x2     = (u16*)w; w += 6291456;   // post-attn residual bf16
  u16* h2     = (u16*)w; w += 6291456;   // v_nat (pre-attn) / lpart (attn) / LN2 out
  u16* qb     = (u16*)w; w += 6291456;   // Q (pre-scaled) [B,H,N,D]
  u16* kb     = (u16*)w; w += 6291456;   // K [B,H,N,D]
  u16* vtb    = (u16*)w; w += 6291456;   // V^T [B,H,D,N]
  u16* ao     = (u16*)w; w += 6291456;   // attn out bf16 [8192][384]
  u16* act    = (u16*)w; w += 25165824;  // Opart f32 (attn) / gelu out
  u16* wqkvb  = (u16*)w; w += 884736;
  u16* wprojb = (u16*)w; w += 294912;
  u16* wfc1b  = (u16*)w; w += 1179648;
  u16* wfc2b  = (u16*)w; w += 1179648;

  u16* v_nat   = h2;           // dead before ln2 writes h2
  float* Opart = (float*)act;  // 2*49152*64*4B = 25165824 B exactly
  float* lpart = (float*)h2;   // after vtr consumed v_nat

  cvt_w<<<6912, 256, 0, stream>>>(wqkv, wproj, wfc1, wfc2, wqkvb, wprojb, wfc1b, wfc2b);
  ln_k<0><<<2048, 256, 0, stream>>>(x, ln1g, ln1b, h1);
  {
    EpiP p{}; p.q = qb; p.k = kb; p.v = v_nat;
    gemm_bt<0, 64><<<1152, 256, 0, stream>>>(h1, wqkvb, 384, 9, p);
  }
  vtr_k<<<dim3(32, 24), 256, 0, stream>>>(v_nat, vtb);
  attn_k<<<dim3(16, 24, 2), 256, 0, stream>>>(qb, kb, vtb, Opart, lpart);
  attn_merge<<<12288, 256, 0, stream>>>(Opart, lpart, ao);
  {
    EpiP p{}; p.bias = bproj; p.residf = x; p.outb = x2;
    gemm_bt<1, 64><<<384, 256, 0, stream>>>(ao, wprojb, 384, 3, p);
  }
  ln_k<1><<<2048, 256, 0, stream>>>(x2, ln2g, ln2b, h2);
  {
    EpiP p{}; p.bias = bfc1; p.outb = act;
    gemm_bt<2, 128><<<768, 256, 0, stream>>>(h2, wfc1b, 384, 12, p);
  }
  {
    EpiP p{}; p.bias = bfc2; p.residb = x2; p.outf = out;
    gemm_bt<3, 64><<<384, 256, 0, stream>>>(act, wfc2b, 1536, 3, p);
  }
}